// Round 7
// baseline (208.357 us; speedup 1.0000x reference)
//
#include <hip/hip_runtime.h>
#include <math.h>

#define DD 64
#define CC 128
#define HH 512
#define BATCH 4096

typedef _Float16 f16;

// prep: W2 (512x512) and W1 ctx rows (64..191) -> fp16 in d_ws
__global__ void to_f16(const float* __restrict__ W1, const float* __restrict__ W2,
                       f16* __restrict__ w2h, f16* __restrict__ w1ch) {
    int idx = blockIdx.x * 256 + threadIdx.x;
    if (idx < HH * HH) w2h[idx] = (f16)W2[idx];
    else               w1ch[idx - HH * HH] = (f16)W1[DD * HH + (idx - HH * HH)];
}

__device__ __forceinline__ float fast_softplus(float x) {
    float t = exp2f(-fabsf(x) * 1.44269504f);
    return fmaxf(x, 0.f) + 0.69314718f * log2f(1.f + t);
}

__device__ __forceinline__ float bcast(float x, int l) {
    return __int_as_float(__builtin_amdgcn_readlane(__float_as_int(x), l));
}

typedef const __attribute__((address_space(1))) void* as1_cptr;
typedef __attribute__((address_space(3))) void* as3_ptr;
__device__ __forceinline__ void glds16(const void* g, float* l) {
    __builtin_amdgcn_global_load_lds((as1_cptr)g, (as3_ptr)l, 16, 0, 0);
}

union HW { float4 f4; f16 h[8]; };

// Block = 2 waves x R=2 rows = 4 batch rows; grid 1024 -> 4 independent barrier
// groups per CU (8 waves/CU). Lane l owns hidden units 8l..8l+7 (deg=(j%63)+1).
// LDS buffer (floats): slots t=0..8 : fp16 W2 rows, 256 floats (1KB) each,
// 16B/lane contiguous (conflict-free b128); offset 2304: f32 W1[i] row in
// split-half layout (1KB + 1KB). Double-buffered; staged via global_load_lds.
// Weight math uses v_fma_mix (fp16 weight, f32 scalar, f32 accum).
// Output accumulation is incremental (R6 scheme): lane c carries
// {mean col c, prescale col 64+c}; z_i extracted by one readlane at step i.
#define SLOT_W1 (9 * 256)
#define BUF_F   (SLOT_W1 + 512)      // 2816 floats = 11264 B

__global__ __launch_bounds__(128, 2) void made_sample(
    const float* __restrict__ ctx,   // (B, C)
    const float* __restrict__ eps,   // (B, D)
    const float* __restrict__ W1,    // (D+C, H) f32 (z-feedback rows)
    const float* __restrict__ b1,    // (H)
    const float* __restrict__ b2,    // (H)
    const float* __restrict__ W3,    // (H, 2D) f32, direct global
    const float* __restrict__ b3,    // (2D)
    const f16*   __restrict__ w2h,   // (H, H) fp16
    const f16*   __restrict__ w1ch,  // (C, H) fp16 (W1 rows 64..191)
    float* __restrict__ out)         // (B, D)
{
    const int lane  = threadIdx.x & 63;
    const int w     = threadIdx.x >> 6;          // wave 0..1
    const int rbase = blockIdx.x * 4 + w * 2;    // 2 batch rows per wave
    const int jbase = 8 * lane;

    __shared__ float sbuf[2][BUF_F];

    int deg[8];
    #pragma unroll
    for (int u = 0; u < 8; ++u) deg[u] = (jbase + u) % 63 + 1;

    float p1[2][8], p2[2][8], acc[2][2];
    #pragma unroll
    for (int u = 0; u < 8; ++u) {
        float t1 = b1[jbase + u], t2 = b2[jbase + u];
        p1[0][u] = t1; p1[1][u] = t1;
        p2[0][u] = t2; p2[1][u] = t2;
    }
    acc[0][0] = 0.f; acc[0][1] = 0.f; acc[1][0] = 0.f; acc[1][1] = 0.f;

    float ca[2], cb[2], ep[2];
    #pragma unroll
    for (int r = 0; r < 2; ++r) {
        ca[r] = ctx[(rbase + r) * CC + lane];
        cb[r] = ctx[(rbase + r) * CC + 64 + lane];
        ep[r] = eps[(rbase + r) * DD + lane];
    }
    const float b3m = b3[lane];
    const float b3p = b3[64 + lane];

    // ctx chunk ch: fp16 W1-ctx rows 8ch..8ch+7 -> slots 0..7 (1 glds16 each)
    auto stage_ctx = [&](int ch, float* buf) {
        #pragma unroll
        for (int q = 0; q < 8; q += 2)
            glds16(w1ch + (8 * ch + q + w) * HH + lane * 8, buf + (q + w) * 256);
    };
    // step `in`: fp16 W2 rows basen+63t (t=0..8; k>=512 -> row 511, mult zeroed)
    // -> slots 0..8; f32 W1 row `in` split-half -> SLOT_W1. 11 ops over 2 waves.
    auto stage_step = [&](int in, float* buf) {
        const int basen = (in == 0) ? 0 : (in - 1);
        #pragma unroll
        for (int o = w; o < 11; o += 2) {
            if (o < 9) {
                int k = basen + 63 * o;
                if (k >= HH) k = HH - 1;
                glds16(w2h + k * HH + lane * 8, buf + o * 256);
            } else if (o == 9) {
                glds16(W1 + in * HH + lane * 8, buf + SLOT_W1);
            } else {
                glds16(W1 + in * HH + lane * 8 + 4, buf + SLOT_W1 + 256);
            }
        }
    };

    // ---- context init: pre1 += ctx @ W1[D:,:], 16 chunks of 8 fp16 rows ----
    stage_ctx(0, sbuf[0]);
    __syncthreads();
    #pragma unroll 1
    for (int ch = 0; ch < 16; ++ch) {
        float* cur = sbuf[ch & 1];
        float* nxt = sbuf[(ch + 1) & 1];
        if (ch < 15) stage_ctx(ch + 1, nxt);
        else         stage_step(0, sbuf[0]);     // 16&1==0: step-0 parity OK
        #pragma unroll
        for (int q = 0; q < 8; ++q) {
            HW uw; uw.f4 = *(const float4*)(cur + q * 256 + lane * 4);
            const int c = 8 * ch + q;
            #pragma unroll
            for (int r = 0; r < 2; ++r) {
                const float cv = bcast((ch < 8) ? ca[r] : cb[r], c & 63);
                #pragma unroll
                for (int u = 0; u < 8; ++u)
                    p1[r][u] = fmaf((float)uw.h[u], cv, p1[r][u]);
            }
        }
        __syncthreads();
    }

    float z[2] = {0.f, 0.f};

    // ---- autoregressive main loop ----
    #pragma unroll 1
    for (int i = 0; i < DD; ++i) {
        float* cur = sbuf[i & 1];
        float* nxt = sbuf[(i + 1) & 1];
        if (i < 63) stage_step(i + 1, nxt);

        const int base = (i == 0) ? 0 : (i - 1);

        // W3 rows finalizing this step — direct global (L2), coalesced
        float w3m[9], w3p[9];
        #pragma unroll
        for (int t = 0; t < 9; ++t) {
            const int k  = base + 63 * t;
            const int ks = (k < HH) ? k : (HH - 1);
            w3m[t] = W3[ks * (2 * DD) + lane];
            w3p[t] = W3[ks * (2 * DD) + 64 + lane];
        }

        // batched LDS preload: 9 fp16 W2 rows + f32 W1 row
        HW w2v[9];
        #pragma unroll
        for (int t = 0; t < 9; ++t)
            w2v[t].f4 = *(const float4*)(cur + t * 256 + lane * 4);
        float w1v[8];
        {
            float4 a = *(const float4*)(cur + SLOT_W1 + lane * 4);
            float4 b = *(const float4*)(cur + SLOT_W1 + 256 + lane * 4);
            w1v[0] = a.x; w1v[1] = a.y; w1v[2] = a.z; w1v[3] = a.w;
            w1v[4] = b.x; w1v[5] = b.y; w1v[6] = b.z; w1v[7] = b.w;
        }

        // (a) finalized h1 (deg==i); zero at i==0
        float m[2];
        #pragma unroll
        for (int r = 0; r < 2; ++r) {
            float mv = 0.f;
            #pragma unroll
            for (int u = 0; u < 8; ++u) mv = (deg[u] == i) ? p1[r][u] : mv;
            m[r] = fmaxf(mv, 0.f);
        }

        // (b) rank-9 update of pre2 (fma_mix: fp16 weight x f32 h + f32 acc)
        #pragma unroll
        for (int t = 0; t < 9; ++t) {
            const int k = base + 63 * t;
            float h0, h1v;
            if (t == 8) {
                const float vm = (k < HH) ? 1.f : 0.f;  // lane 63 for k in [504,512)
                h0  = vm * bcast(m[0], 63);
                h1v = vm * bcast(m[1], 63);
            } else {
                h0  = bcast(m[0], k >> 3);
                h1v = bcast(m[1], k >> 3);
            }
            #pragma unroll
            for (int u = 0; u < 8; ++u) {
                p2[0][u] = fmaf((float)w2v[t].h[u], h0,  p2[0][u]);
                p2[1][u] = fmaf((float)w2v[t].h[u], h1v, p2[1][u]);
            }
        }

        // (c) newly-final h2 (deg==i)
        float hn[2];
        #pragma unroll
        for (int r = 0; r < 2; ++r) {
            float hv = 0.f;
            #pragma unroll
            for (int u = 0; u < 8; ++u) hv = (deg[u] == i) ? p2[r][u] : hv;
            hn[r] = fmaxf(hv, 0.f);
        }

        // (d) incremental output acc: acc += h2[k_t] * {W3[k_t,c], W3[k_t,64+c]}
        #pragma unroll
        for (int t = 0; t < 9; ++t) {
            const int k = base + 63 * t;
            float h0, h1v;
            if (t == 8) {
                const float vm = (k < HH) ? 1.f : 0.f;
                h0  = vm * bcast(hn[0], 63);
                h1v = vm * bcast(hn[1], 63);
            } else {
                h0  = bcast(hn[0], k >> 3);
                h1v = bcast(hn[1], k >> 3);
            }
            acc[0][0] = fmaf(h0,  w3m[t], acc[0][0]);
            acc[0][1] = fmaf(h0,  w3p[t], acc[0][1]);
            acc[1][0] = fmaf(h1v, w3m[t], acc[1][0]);
            acc[1][1] = fmaf(h1v, w3p[t], acc[1][1]);
        }

        // (e) z_i: column i's totals live in lane i
        #pragma unroll
        for (int r = 0; r < 2; ++r) {
            const float am = acc[r][0] + b3m;
            const float ap = acc[r][1] + b3p;
            const float sp = fast_softplus(ap);
            const float zc = fmaf(sp, ep[r], am);
            const float zi = bcast(zc, i);
            if (lane == i) z[r] = zi;
            #pragma unroll
            for (int u = 0; u < 8; ++u) p1[r][u] = fmaf(zi, w1v[u], p1[r][u]);
        }

        __syncthreads();
    }

    #pragma unroll
    for (int r = 0; r < 2; ++r) out[(rbase + r) * DD + lane] = z[r];
}

extern "C" void kernel_launch(void* const* d_in, const int* in_sizes, int n_in,
                              void* d_out, int out_size, void* d_ws, size_t ws_size,
                              hipStream_t stream) {
    const float* ctx = (const float*)d_in[0];
    const float* eps = (const float*)d_in[1];
    const float* W1  = (const float*)d_in[2];
    const float* b1  = (const float*)d_in[3];
    const float* W2  = (const float*)d_in[4];
    const float* b2  = (const float*)d_in[5];
    const float* W3  = (const float*)d_in[6];
    const float* b3  = (const float*)d_in[7];

    f16* w2h  = (f16*)d_ws;                    // 512*512 halfs
    f16* w1ch = w2h + HH * HH;                 // 128*512 halfs (total 640 KB)

    to_f16<<<(HH * HH + CC * HH) / 256, 256, 0, stream>>>(W1, W2, w2h, w1ch);
    made_sample<<<BATCH / 4, 128, 0, stream>>>(ctx, eps, W1, b1, b2, W3, b3,
                                               w2h, w1ch, (float*)d_out);
}

// Round 8
// 198.022 us; speedup vs baseline: 1.0522x; 1.0522x over previous
//
#include <hip/hip_runtime.h>
#include <math.h>

#define DD 64
#define CC 128
#define HH 512
#define BATCH 4096

typedef __attribute__((ext_vector_type(2))) float f32x2;

__device__ __forceinline__ f32x2 splat2(float x) { f32x2 v; v[0] = x; v[1] = x; return v; }

__device__ __forceinline__ float fast_softplus(float x) {
    float t = exp2f(-fabsf(x) * 1.44269504f);
    return fmaxf(x, 0.f) + 0.69314718f * log2f(1.f + t);
}

// wave-uniform broadcast via v_readlane -> SGPR (int form enables scalar branch)
__device__ __forceinline__ int bcasti(float x, int l) {
    return __builtin_amdgcn_readlane(__float_as_int(x), l);
}
__device__ __forceinline__ float bcast(float x, int l) {
    return __int_as_float(bcasti(x, l));
}

typedef const __attribute__((address_space(1))) void* as1_cptr;
typedef __attribute__((address_space(3))) void* as3_ptr;
__device__ __forceinline__ void glds16(const float* g, float* l) {
    __builtin_amdgcn_global_load_lds((as1_cptr)g, (as3_ptr)l, 16, 0, 0);
}

// Single kernel. Block = 2 waves x R=2 rows = 4 batch rows; grid 1024 ->
// 4 independent barrier groups per CU (8 waves/CU, LDS-limited: 4x36KB=144KB).
// Lane l owns hidden units 8l..8l+7, deg=(j%63)+1. Split-half LDS layout per
// 512-float row (elems 8l..8l+3 at +16B*l, 8l+4..8l+7 at +1KB+16B*l):
// conflict-free b128 reads, glds16-stageable.
// 9 W2 rows (8 for i>8) double-buffered in LDS; W1[i] feedback row and the 9
// W3 rows read direct-global (L2-hot, coalesced).
// Zero-skip: broadcast h sits in SGPR -> uniform s_cbranch skips LDS read +
// 8 pk_fma whenever both rows' h==0 (relu emits exact +0), per-row inner ifs.
__global__ __launch_bounds__(128, 2) void made_sample(
    const float* __restrict__ ctx,   // (B, C)
    const float* __restrict__ eps,   // (B, D)
    const float* __restrict__ W1,    // (D+C, H)
    const float* __restrict__ b1,    // (H)
    const float* __restrict__ W2,    // (H, H)
    const float* __restrict__ b2,    // (H)
    const float* __restrict__ W3,    // (H, 2D)
    const float* __restrict__ b3,    // (2D)
    float* __restrict__ out)         // (B, D)
{
    const int lane  = threadIdx.x & 63;
    const int w     = threadIdx.x >> 6;          // wave 0..1
    const int rbase = blockIdx.x * 4 + w * 2;    // 2 batch rows per wave
    const int jbase = 8 * lane;

    __shared__ float sbuf[2][9 * HH];            // 2 x 18 KB

    int deg[8];
    #pragma unroll
    for (int u = 0; u < 8; ++u) deg[u] = (jbase + u) % 63 + 1;

    // split-half LDS read: slot base -> 4 f32x2 (8 floats) for this lane
    auto load8v = [&](const float* base_, f32x2* r_) {
        float4 a = *(const float4*)(base_ + lane * 4);
        float4 b = *(const float4*)(base_ + 256 + lane * 4);
        r_[0][0] = a.x; r_[0][1] = a.y; r_[1][0] = a.z; r_[1][1] = a.w;
        r_[2][0] = b.x; r_[2][1] = b.y; r_[3][0] = b.z; r_[3][1] = b.w;
    };

    f32x2 p1[2][4], p2[2][4], acc[2];
    #pragma unroll
    for (int j = 0; j < 4; ++j) {
        f32x2 t1, t2;
        t1[0] = b1[jbase + 2 * j]; t1[1] = b1[jbase + 2 * j + 1];
        t2[0] = b2[jbase + 2 * j]; t2[1] = b2[jbase + 2 * j + 1];
        p1[0][j] = t1; p1[1][j] = t1;
        p2[0][j] = t2; p2[1][j] = t2;
    }
    acc[0] = splat2(0.f);
    acc[1] = splat2(0.f);

    float ca[2], cb[2], ep[2];
    #pragma unroll
    for (int r = 0; r < 2; ++r) {
        ca[r] = ctx[(rbase + r) * CC + lane];
        cb[r] = ctx[(rbase + r) * CC + 64 + lane];
        ep[r] = eps[(rbase + r) * DD + lane];
    }
    const float b3m = b3[lane];
    const float b3p = b3[64 + lane];

    // ctx chunk ch: W1 rows DD+8ch..DD+8ch+7 -> slots 0..7 (16 glds over 2 waves)
    auto stage_ctx = [&](int ch, float* buf) {
        #pragma unroll
        for (int o = 0; o < 8; ++o) {
            const int oo = 2 * o + w;            // 0..15
            const int r = oo >> 1, hf = oo & 1;
            glds16(W1 + (DD + 8 * ch + r) * HH + lane * 8 + hf * 4,
                   buf + r * HH + hf * 256);
        }
    };
    // step `in`: W2 rows (in==0?0:in-1)+63t -> slots t. 9 rows if in<=8 else 8.
    auto stage_step = [&](int in, float* buf) {
        const int basen = (in == 0) ? 0 : (in - 1);
        const int nops = (in <= 8) ? 18 : 16;
        #pragma unroll
        for (int o = 0; o < 9; ++o) {
            const int oo = 2 * o + w;            // 0..17
            if (oo < nops) {
                const int r = oo >> 1, hf = oo & 1;
                glds16(W2 + (basen + 63 * r) * HH + lane * 8 + hf * 4,
                       buf + r * HH + hf * 256);
            }
        }
    };

    // ---- context init: pre1 += ctx @ W1[D:,:], 16 chunks of 8 rows ----
    stage_ctx(0, sbuf[0]);
    __syncthreads();
    #pragma unroll 1
    for (int ch = 0; ch < 16; ++ch) {
        float* cur = sbuf[ch & 1];
        float* nxt = sbuf[(ch + 1) & 1];
        if (ch < 15) stage_ctx(ch + 1, nxt);
        else         stage_step(0, sbuf[0]);     // 16&1==0: step-0 parity OK
        #pragma unroll
        for (int q = 0; q < 8; ++q) {
            f32x2 wv[4];
            load8v(cur + q * HH, wv);
            const int c = 8 * ch + q;
            #pragma unroll
            for (int r = 0; r < 2; ++r) {
                const float cv = bcast((ch < 8) ? ca[r] : cb[r], c & 63);
                const f32x2 cv2 = splat2(cv);
                #pragma unroll
                for (int j = 0; j < 4; ++j) p1[r][j] += cv2 * wv[j];
            }
        }
        __syncthreads();
    }

    float z[2] = {0.f, 0.f};

    // ---- autoregressive main loop ----
    #pragma unroll 1
    for (int i = 0; i < DD; ++i) {
        float* cur = sbuf[i & 1];
        float* nxt = sbuf[(i + 1) & 1];
        if (i < 63) stage_step(i + 1, nxt);

        const int base = (i == 0) ? 0 : (i - 1);

        // direct-global preloads (L2-hot, off the serial chain)
        f32x2 w3v[9];
        #pragma unroll
        for (int t = 0; t < 8; ++t) {
            const int k = base + 63 * t;
            w3v[t][0] = W3[k * (2 * DD) + lane];
            w3v[t][1] = W3[k * (2 * DD) + 64 + lane];
        }
        if (i <= 8) {
            const int k = base + 504;
            w3v[8][0] = W3[k * (2 * DD) + lane];
            w3v[8][1] = W3[k * (2 * DD) + 64 + lane];
        }
        f32x2 w1v[4];
        {
            float4 a = *(const float4*)(W1 + i * HH + lane * 8);
            float4 b = *(const float4*)(W1 + i * HH + lane * 8 + 4);
            w1v[0][0] = a.x; w1v[0][1] = a.y; w1v[1][0] = a.z; w1v[1][1] = a.w;
            w1v[2][0] = b.x; w1v[2][1] = b.y; w1v[3][0] = b.z; w1v[3][1] = b.w;
        }

        // (a) finalized h1 (deg==i); zero at i==0
        float m[2];
        #pragma unroll
        for (int r = 0; r < 2; ++r) {
            float mv = 0.f;
            #pragma unroll
            for (int u = 0; u < 8; ++u)
                mv = (deg[u] == i) ? p1[r][u >> 1][u & 1] : mv;
            m[r] = fmaxf(mv, 0.f);
        }

        // (b) rank update of pre2; zero-skip via uniform scalar branches
        #pragma unroll
        for (int t = 0; t < 8; ++t) {
            const int k = base + 63 * t;
            const int hb0 = bcasti(m[0], k >> 3);
            const int hb1 = bcasti(m[1], k >> 3);
            if (hb0 | hb1) {
                f32x2 wv[4];
                load8v(cur + t * HH, wv);
                if (hb0) {
                    const f32x2 h = splat2(__int_as_float(hb0));
                    #pragma unroll
                    for (int j = 0; j < 4; ++j) p2[0][j] += h * wv[j];
                }
                if (hb1) {
                    const f32x2 h = splat2(__int_as_float(hb1));
                    #pragma unroll
                    for (int j = 0; j < 4; ++j) p2[1][j] += h * wv[j];
                }
            }
        }
        if (i <= 8) {                            // t=8: k=base+504 in [504,511]
            const int hb0 = bcasti(m[0], 63);
            const int hb1 = bcasti(m[1], 63);
            if (hb0 | hb1) {
                f32x2 wv[4];
                load8v(cur + 8 * HH, wv);
                if (hb0) {
                    const f32x2 h = splat2(__int_as_float(hb0));
                    #pragma unroll
                    for (int j = 0; j < 4; ++j) p2[0][j] += h * wv[j];
                }
                if (hb1) {
                    const f32x2 h = splat2(__int_as_float(hb1));
                    #pragma unroll
                    for (int j = 0; j < 4; ++j) p2[1][j] += h * wv[j];
                }
            }
        }

        // (c) newly-final h2 (deg==i)
        float hn[2];
        #pragma unroll
        for (int r = 0; r < 2; ++r) {
            float hv = 0.f;
            #pragma unroll
            for (int u = 0; u < 8; ++u)
                hv = (deg[u] == i) ? p2[r][u >> 1][u & 1] : hv;
            hn[r] = fmaxf(hv, 0.f);
        }

        // (d) incremental output acc: acc += h2[k_t] * {W3[k_t,lane], W3[k_t,64+lane]}
        #pragma unroll
        for (int t = 0; t < 8; ++t) {
            const int k = base + 63 * t;
            acc[0] += splat2(bcast(hn[0], k >> 3)) * w3v[t];
            acc[1] += splat2(bcast(hn[1], k >> 3)) * w3v[t];
        }
        if (i <= 8) {
            acc[0] += splat2(bcast(hn[0], 63)) * w3v[8];
            acc[1] += splat2(bcast(hn[1], 63)) * w3v[8];
        }

        // (e) z_i: column i's totals live in lane i; all lanes compute, one readlane
        #pragma unroll
        for (int r = 0; r < 2; ++r) {
            const float am = acc[r][0] + b3m;
            const float ap = acc[r][1] + b3p;
            const float sp = fast_softplus(ap);
            const float zc = fmaf(sp, ep[r], am);
            const float zi = bcast(zc, i);
            if (lane == i) z[r] = zi;
            const f32x2 zi2 = splat2(zi);
            #pragma unroll
            for (int j = 0; j < 4; ++j) p1[r][j] += zi2 * w1v[j];
        }

        __syncthreads();
    }

    #pragma unroll
    for (int r = 0; r < 2; ++r) out[(rbase + r) * DD + lane] = z[r];
}

extern "C" void kernel_launch(void* const* d_in, const int* in_sizes, int n_in,
                              void* d_out, int out_size, void* d_ws, size_t ws_size,
                              hipStream_t stream) {
    const float* ctx = (const float*)d_in[0];
    const float* eps = (const float*)d_in[1];
    const float* W1  = (const float*)d_in[2];
    const float* b1  = (const float*)d_in[3];
    const float* W2  = (const float*)d_in[4];
    const float* b2  = (const float*)d_in[5];
    const float* W3  = (const float*)d_in[6];
    const float* b3  = (const float*)d_in[7];
    (void)d_ws; (void)ws_size; (void)in_sizes; (void)n_in; (void)out_size;

    made_sample<<<BATCH / 4, 128, 0, stream>>>(ctx, eps, W1, b1, W2, b2, W3, b3,
                                               (float*)d_out);
}